// Round 2
// baseline (555.333 us; speedup 1.0000x reference)
//
#include <hip/hip_runtime.h>
#include <hip/hip_bf16.h>

typedef unsigned short u16;
typedef __attribute__((ext_vector_type(8))) short short8;   // 8 bf16 = 4 VGPRs
typedef __attribute__((ext_vector_type(4))) float f32x4;

__device__ __forceinline__ float bf2f(u16 v) {
    union { unsigned u; float f; } c; c.u = ((unsigned)v) << 16; return c.f;
}
__device__ __forceinline__ u16 f2bf(float f) {
    union { float f; unsigned u; } c; c.f = f;
    unsigned r = c.u + 0x7fffu + ((c.u >> 16) & 1u);   // RNE
    return (u16)(r >> 16);
}
__device__ __forceinline__ uint4 pack8(const float4 a, const float4 b) {
    uint4 r;
    r.x = (unsigned)f2bf(a.x) | ((unsigned)f2bf(a.y) << 16);
    r.y = (unsigned)f2bf(a.z) | ((unsigned)f2bf(a.w) << 16);
    r.z = (unsigned)f2bf(b.x) | ((unsigned)f2bf(b.y) << 16);
    r.w = (unsigned)f2bf(b.z) | ((unsigned)f2bf(b.w) << 16);
    return r;
}

#define GM 8192   // B*S
#define GN 1024   // D
#define GK 1024   // D

// C = A (M x K row-major) * B^T  (B is (N,K) row-major f32 torch weight).
// A_IS_F32: A is f32 (else bf16).  OUT_F32: C is f32 row-major (scatter ignored).
// scatter (bf16 out only): C[((b*16+h)*2048+s)*64+d], b=row>>11, s=row&2047, h=col>>6, d=col&63.
template<int A_IS_F32, int OUT_F32>
__global__ __launch_bounds__(256) void gemm_bt(const void* __restrict__ Av,
                                               const float* __restrict__ Bw,
                                               void* __restrict__ Cv,
                                               float scale, int scatter) {
    __shared__ u16 As[64][72];
    __shared__ u16 Bs[64][72];

    const int tid  = threadIdx.x;
    const int wave = tid >> 6;
    const int lane = tid & 63;
    const int lr   = lane & 15;   // fragment row/col
    const int quad = lane >> 4;   // 0..3
    const int wm   = (wave >> 1) * 32;
    const int wn   = (wave & 1) * 32;
    const int m0   = blockIdx.y * 64;
    const int n0   = blockIdx.x * 64;

    f32x4 acc[2][2];
    for (int i = 0; i < 2; ++i)
        for (int j = 0; j < 2; ++j)
            acc[i][j] = 0;

    const int sr = tid >> 3;          // 0..31
    const int scol = (tid & 7) << 3;  // 0..56 step 8

    for (int kt = 0; kt < GK; kt += 64) {
        __syncthreads();
        for (int half = 0; half < 2; ++half) {
            int r = sr + half * 32;
            if (A_IS_F32) {
                const float* A = (const float*)Av;
                float4 a0 = *(const float4*)&A[(size_t)(m0 + r) * GK + kt + scol];
                float4 a1 = *(const float4*)&A[(size_t)(m0 + r) * GK + kt + scol + 4];
                *(uint4*)&As[r][scol] = pack8(a0, a1);
            } else {
                const u16* A = (const u16*)Av;
                *(uint4*)&As[r][scol] = *(const uint4*)&A[(size_t)(m0 + r) * GK + kt + scol];
            }
            float4 b0 = *(const float4*)&Bw[(size_t)(n0 + r) * GK + kt + scol];
            float4 b1 = *(const float4*)&Bw[(size_t)(n0 + r) * GK + kt + scol + 4];
            *(uint4*)&Bs[r][scol] = pack8(b0, b1);
        }
        __syncthreads();
        for (int kk = 0; kk < 2; ++kk) {
            short8 a0 = *(const short8*)&As[wm + lr][kk * 32 + quad * 8];
            short8 a1 = *(const short8*)&As[wm + 16 + lr][kk * 32 + quad * 8];
            short8 b0 = *(const short8*)&Bs[wn + lr][kk * 32 + quad * 8];
            short8 b1 = *(const short8*)&Bs[wn + 16 + lr][kk * 32 + quad * 8];
            acc[0][0] = __builtin_amdgcn_mfma_f32_16x16x32_bf16(a0, b0, acc[0][0], 0, 0, 0);
            acc[0][1] = __builtin_amdgcn_mfma_f32_16x16x32_bf16(a0, b1, acc[0][1], 0, 0, 0);
            acc[1][0] = __builtin_amdgcn_mfma_f32_16x16x32_bf16(a1, b0, acc[1][0], 0, 0, 0);
            acc[1][1] = __builtin_amdgcn_mfma_f32_16x16x32_bf16(a1, b1, acc[1][1], 0, 0, 0);
        }
    }

    for (int mi = 0; mi < 2; ++mi) {
        for (int ni = 0; ni < 2; ++ni) {
            for (int reg = 0; reg < 4; ++reg) {
                int row = m0 + wm + mi * 16 + quad * 4 + reg;
                int col = n0 + wn + ni * 16 + lr;
                float v = acc[mi][ni][reg] * scale;
                if (OUT_F32) {
                    ((float*)Cv)[(size_t)row * GN + col] = v;
                } else {
                    u16 bv = f2bf(v);
                    if (scatter) {
                        int b = row >> 11, s = row & 2047, h = col >> 6, d = col & 63;
                        ((u16*)Cv)[(((size_t)(b * 16 + h) * 2048) + s) * 64 + d] = bv;
                    } else {
                        ((u16*)Cv)[(size_t)row * GN + col] = bv;
                    }
                }
            }
        }
    }
}

// Flash-style causal attention. Q,K,V: (B*H, S=2048, dk=64) bf16, Q pre-scaled by 0.125.
// O: (B, S, 1024) bf16 at column h*64+d.
__global__ __launch_bounds__(256) void attn_kernel(const u16* __restrict__ Q,
                                                   const u16* __restrict__ Kg,
                                                   const u16* __restrict__ V,
                                                   u16* __restrict__ O) {
    __shared__ u16 Qs[64][72];
    __shared__ u16 Ks[64][72];
    __shared__ u16 Vt[64][72];      // transposed: Vt[d][key]
    __shared__ u16 Ps[4][16][72];   // per-wave P staging (C-layout -> A-layout)

    const int tid  = threadIdx.x;
    const int wave = tid >> 6;
    const int lane = tid & 63;
    const int lr   = lane & 15;
    const int quad = lane >> 4;
    const int qt    = blockIdx.x;       // 0..31
    const int bh    = blockIdx.y;       // 0..63
    const int qbase = qt * 64;
    const size_t base = (size_t)bh * 2048 * 64;

    {
        int sr = tid >> 3, scol = (tid & 7) << 3;
        for (int half = 0; half < 2; ++half) {
            int r = sr + half * 32;
            *(uint4*)&Qs[r][scol] = *(const uint4*)&Q[base + (size_t)(qbase + r) * 64 + scol];
        }
    }
    __syncthreads();
    short8 qa[2];
    qa[0] = *(const short8*)&Qs[wave * 16 + lr][quad * 8];
    qa[1] = *(const short8*)&Qs[wave * 16 + lr][32 + quad * 8];

    float m_r[4], l_r[4];
    f32x4 oacc[4];
    for (int i = 0; i < 4; ++i) { m_r[i] = -3.0e38f; l_r[i] = 0.f; oacc[i] = 0; }

    for (int j = 0; j <= qt; ++j) {
        __syncthreads();
        {
            int sr = tid >> 3, scol = (tid & 7) << 3;
            for (int half = 0; half < 2; ++half) {
                int r = sr + half * 32;
                *(uint4*)&Ks[r][scol] = *(const uint4*)&Kg[base + (size_t)(j * 64 + r) * 64 + scol];
            }
            int vk = tid >> 2;           // key 0..63
            int vd = (tid & 3) << 4;     // 0,16,32,48
            uint4 v0 = *(const uint4*)&V[base + (size_t)(j * 64 + vk) * 64 + vd];
            uint4 v1 = *(const uint4*)&V[base + (size_t)(j * 64 + vk) * 64 + vd + 8];
            const u16* pv0 = (const u16*)&v0;
            const u16* pv1 = (const u16*)&v1;
            for (int i = 0; i < 8; ++i) Vt[vd + i][vk] = pv0[i];
            for (int i = 0; i < 8; ++i) Vt[vd + 8 + i][vk] = pv1[i];
        }
        __syncthreads();

        f32x4 sc4[4];
        for (int ni = 0; ni < 4; ++ni) sc4[ni] = 0;
        for (int kk = 0; kk < 2; ++kk) {
            for (int ni = 0; ni < 4; ++ni) {
                short8 kb = *(const short8*)&Ks[ni * 16 + lr][kk * 32 + quad * 8];
                sc4[ni] = __builtin_amdgcn_mfma_f32_16x16x32_bf16(qa[kk], kb, sc4[ni], 0, 0, 0);
            }
        }
        if (j == qt) {   // diagonal tile: causal mask
            for (int ni = 0; ni < 4; ++ni) {
                int key = j * 64 + ni * 16 + lr;
                for (int reg = 0; reg < 4; ++reg) {
                    int qr = qbase + wave * 16 + quad * 4 + reg;
                    if (key > qr) sc4[ni][reg] = -3.0e38f;
                }
            }
        }

        float alpha[4];
        for (int reg = 0; reg < 4; ++reg) {
            float mx = fmaxf(fmaxf(sc4[0][reg], sc4[1][reg]), fmaxf(sc4[2][reg], sc4[3][reg]));
            for (int off = 1; off < 16; off <<= 1) mx = fmaxf(mx, __shfl_xor(mx, off, 64));
            float mnew = fmaxf(m_r[reg], mx);
            alpha[reg] = __expf(m_r[reg] - mnew);
            m_r[reg] = mnew;
        }
        float rs[4] = {0.f, 0.f, 0.f, 0.f};
        for (int ni = 0; ni < 4; ++ni) {
            for (int reg = 0; reg < 4; ++reg) {
                float p = __expf(sc4[ni][reg] - m_r[reg]);
                u16 pb = f2bf(p);
                rs[reg] += bf2f(pb);             // l consistent with bf16 P used in PV
                Ps[wave][quad * 4 + reg][ni * 16 + lr] = pb;
            }
        }
        for (int reg = 0; reg < 4; ++reg) {
            float s = rs[reg];
            for (int off = 1; off < 16; off <<= 1) s += __shfl_xor(s, off, 64);
            l_r[reg] = l_r[reg] * alpha[reg] + s;
        }
        for (int dn = 0; dn < 4; ++dn)
            for (int reg = 0; reg < 4; ++reg)
                oacc[dn][reg] *= alpha[reg];

        __syncthreads();   // ensure P visible before PV reads (ordering hedge)

        // PV: P in per-wave LDS region
        for (int c = 0; c < 2; ++c) {
            short8 pa = *(const short8*)&Ps[wave][lr][c * 32 + quad * 8];
            for (int dn = 0; dn < 4; ++dn) {
                short8 vb = *(const short8*)&Vt[dn * 16 + lr][c * 32 + quad * 8];
                oacc[dn] = __builtin_amdgcn_mfma_f32_16x16x32_bf16(pa, vb, oacc[dn], 0, 0, 0);
            }
        }
    }

    const int b = bh >> 4, h = bh & 15;
    for (int dn = 0; dn < 4; ++dn) {
        for (int reg = 0; reg < 4; ++reg) {
            int s = qbase + wave * 16 + quad * 4 + reg;
            int d = dn * 16 + lr;
            float v = oacc[dn][reg] / l_r[reg];
            O[((size_t)(b * 2048 + s)) * 1024 + h * 64 + d] = f2bf(v);
        }
    }
}

extern "C" void kernel_launch(void* const* d_in, const int* in_sizes, int n_in,
                              void* d_out, int out_size, void* d_ws, size_t ws_size,
                              hipStream_t stream) {
    const float* x  = (const float*)d_in[0];
    const float* Wq = (const float*)d_in[1];
    const float* Wk = (const float*)d_in[2];
    const float* Wv = (const float*)d_in[3];
    const float* Wo = (const float*)d_in[4];

    // workspace: Q,K,V in (B,H,S,dk) bf16 + O in (B,S,D) bf16 = 64 MB total
    u16* qb = (u16*)d_ws;
    u16* kb = qb + (size_t)8388608;
    u16* vb = kb + (size_t)8388608;
    u16* ob = vb + (size_t)8388608;

    dim3 gblk(GN / 64, GM / 64);  // (16, 128)
    gemm_bt<1, 0><<<gblk, 256, 0, stream>>>(x, Wq, qb, 0.125f, 1);  // Q pre-scaled by 1/sqrt(dk)
    gemm_bt<1, 0><<<gblk, 256, 0, stream>>>(x, Wk, kb, 1.0f, 1);
    gemm_bt<1, 0><<<gblk, 256, 0, stream>>>(x, Wv, vb, 1.0f, 1);

    attn_kernel<<<dim3(32, 64), 256, 0, stream>>>(qb, kb, vb, ob);

    gemm_bt<0, 1><<<gblk, 256, 0, stream>>>(ob, Wo, (float*)d_out, 1.0f, 0);
}

// Round 3
// 324.854 us; speedup vs baseline: 1.7095x; 1.7095x over previous
//
#include <hip/hip_runtime.h>
#include <hip/hip_bf16.h>

typedef unsigned short u16;
typedef __attribute__((ext_vector_type(8))) short short8;   // 8 bf16 = 4 VGPRs
typedef __attribute__((ext_vector_type(4))) float f32x4;

__device__ __forceinline__ float bf2f(u16 v) {
    union { unsigned u; float f; } c; c.u = ((unsigned)v) << 16; return c.f;
}
__device__ __forceinline__ u16 f2bf(float f) {
    union { float f; unsigned u; } c; c.f = f;
    unsigned r = c.u + 0x7fffu + ((c.u >> 16) & 1u);   // RNE
    return (u16)(r >> 16);
}
__device__ __forceinline__ uint4 pack8(const float4 a, const float4 b) {
    uint4 r;
    r.x = (unsigned)f2bf(a.x) | ((unsigned)f2bf(a.y) << 16);
    r.y = (unsigned)f2bf(a.z) | ((unsigned)f2bf(a.w) << 16);
    r.z = (unsigned)f2bf(b.x) | ((unsigned)f2bf(b.y) << 16);
    r.w = (unsigned)f2bf(b.z) | ((unsigned)f2bf(b.w) << 16);
    return r;
}

// ---- one-shot f32 -> bf16 conversion of x + 4 weights -------------------
__global__ __launch_bounds__(256) void convert_all(const float* __restrict__ x,
                                                   const float* __restrict__ wq,
                                                   const float* __restrict__ wk,
                                                   const float* __restrict__ wv,
                                                   const float* __restrict__ wo,
                                                   u16* xb, u16* wqb, u16* wkb, u16* wvb, u16* wob) {
    size_t i8 = ((size_t)blockIdx.x * 256 + threadIdx.x) * 8;
    const float* src; u16* dst; size_t off;
    if (i8 < 8388608) { src = x; dst = xb; off = i8; }
    else {
        size_t idx = i8 - 8388608;
        int w = (int)(idx >> 20); off = idx & 1048575;
        src = (w == 0) ? wq : (w == 1) ? wk : (w == 2) ? wv : wo;
        dst = (w == 0) ? wqb : (w == 1) ? wkb : (w == 2) ? wvb : wob;
    }
    float4 a = *(const float4*)&src[off];
    float4 b = *(const float4*)&src[off + 4];
    *(uint4*)&dst[off] = pack8(a, b);
}

// ---- 128x128-tile bf16 GEMM: C = A * B^T  (A: MxK row-major, B: NxK row-major)
// MODE 0: bf16 out, scatter (b*16+h, s, d) from (row=s, col=h*64+d), scaled
// MODE 1: bf16 out, V^T scatter (b*16+h, d, s) from (row=h*64+d, col=s)
// MODE 2: f32 out, row-major C[row*N+col]
template<int MODE>
__global__ __launch_bounds__(256) void gemm128(const u16* __restrict__ A,
                                               const u16* __restrict__ B,
                                               void* __restrict__ C,
                                               int N, int Kdim, float scale) {
    __shared__ u16 As[128][72];
    __shared__ u16 Bs[128][72];
    const int tid  = threadIdx.x;
    const int wave = tid >> 6, lane = tid & 63, lr = lane & 15, quad = lane >> 4;
    const int wm = (wave >> 1) * 64, wn = (wave & 1) * 64;
    const int m0 = blockIdx.y * 128, n0 = blockIdx.x * 128;

    f32x4 acc[4][4];
    for (int i = 0; i < 4; ++i)
        for (int j = 0; j < 4; ++j) acc[i][j] = 0;

    for (int kt = 0; kt < Kdim; kt += 64) {
        __syncthreads();
        #pragma unroll
        for (int i = 0; i < 4; ++i) {
            int id = tid + i * 256;
            int row = id >> 3, c8 = (id & 7) << 3;
            *(uint4*)&As[row][c8] = *(const uint4*)&A[(size_t)(m0 + row) * Kdim + kt + c8];
            *(uint4*)&Bs[row][c8] = *(const uint4*)&B[(size_t)(n0 + row) * Kdim + kt + c8];
        }
        __syncthreads();
        #pragma unroll
        for (int c = 0; c < 2; ++c) {
            short8 af[4], bf[4];
            #pragma unroll
            for (int mi = 0; mi < 4; ++mi) af[mi] = *(const short8*)&As[wm + mi * 16 + lr][c * 32 + quad * 8];
            #pragma unroll
            for (int ni = 0; ni < 4; ++ni) bf[ni] = *(const short8*)&Bs[wn + ni * 16 + lr][c * 32 + quad * 8];
            #pragma unroll
            for (int mi = 0; mi < 4; ++mi)
                #pragma unroll
                for (int ni = 0; ni < 4; ++ni)
                    acc[mi][ni] = __builtin_amdgcn_mfma_f32_16x16x32_bf16(af[mi], bf[ni], acc[mi][ni], 0, 0, 0);
        }
    }

    #pragma unroll
    for (int mi = 0; mi < 4; ++mi)
        #pragma unroll
        for (int ni = 0; ni < 4; ++ni)
            #pragma unroll
            for (int reg = 0; reg < 4; ++reg) {
                int row = m0 + wm + mi * 16 + quad * 4 + reg;
                int col = n0 + wn + ni * 16 + lr;
                float v = acc[mi][ni][reg] * scale;
                if (MODE == 2) {
                    ((float*)C)[(size_t)row * N + col] = v;
                } else if (MODE == 0) {
                    int bh = (row >> 11) * 16 + (col >> 6);
                    ((u16*)C)[(size_t)bh * 131072 + (size_t)(row & 2047) * 64 + (col & 63)] = f2bf(v);
                } else {
                    int bh = (col >> 11) * 16 + (row >> 6);
                    ((u16*)C)[(size_t)bh * 131072 + (size_t)(row & 63) * 2048 + (col & 2047)] = f2bf(v);
                }
            }
}

// ---- barrier-free flash attention, transposed-score formulation ----------
// Q,K: (bh, s, 64) bf16 (Q pre-scaled by 0.125). Vt: (bh, 64, s) bf16.
// O: (B, S, 1024) bf16. One wave = 32 q-rows; no __syncthreads anywhere.
__global__ __launch_bounds__(256) void attn_kernel(const u16* __restrict__ Q,
                                                   const u16* __restrict__ K,
                                                   const u16* __restrict__ Vt,
                                                   u16* __restrict__ O) {
    __shared__ u16 Ps[4][2][16][72];   // per-wave P^T staging (C-layout -> B-frag)

    const int tid = threadIdx.x, wave = tid >> 6, lane = tid & 63;
    const int lr = lane & 15, quad = lane >> 4;
    const int blk = blockIdx.x;
    const int bh = blk & 63;                       // bh % 8 locked to XCD for L2 locality
    const int gp = (blk >> 6) * 4 + wave;          // 0..63
    const int g  = 63 - gp;                        // heavy groups first
    const int qbase = g * 32;
    const size_t base = (size_t)bh * 131072;

    short8 qf[2][2];
    #pragma unroll
    for (int qmi = 0; qmi < 2; ++qmi)
        #pragma unroll
        for (int c = 0; c < 2; ++c)
            qf[qmi][c] = *(const short8*)&Q[base + (size_t)(qbase + qmi * 16 + lr) * 64 + c * 32 + quad * 8];

    float m_r[2] = {-3.0e38f, -3.0e38f}, l_r[2] = {0.f, 0.f};
    f32x4 oacc[4][2];   // [dmi][qmi], holds O^T fragments: d=dmi*16+quad*4+reg, q=lr
    #pragma unroll
    for (int i = 0; i < 4; ++i) { oacc[i][0] = 0; oacc[i][1] = 0; }

    const int jmax = g >> 1;
    for (int j = 0; j <= jmax; ++j) {
        short8 kf[4][2];
        #pragma unroll
        for (int ni = 0; ni < 4; ++ni)
            #pragma unroll
            for (int c = 0; c < 2; ++c)
                kf[ni][c] = *(const short8*)&K[base + (size_t)(j * 64 + ni * 16 + lr) * 64 + c * 32 + quad * 8];

        f32x4 st[4][2];   // S^T fragments: key=j*64+ni*16+quad*4+reg, q=qbase+qmi*16+lr
        #pragma unroll
        for (int ni = 0; ni < 4; ++ni) { st[ni][0] = 0; st[ni][1] = 0; }
        #pragma unroll
        for (int c = 0; c < 2; ++c)
            #pragma unroll
            for (int ni = 0; ni < 4; ++ni)
                #pragma unroll
                for (int qmi = 0; qmi < 2; ++qmi)
                    st[ni][qmi] = __builtin_amdgcn_mfma_f32_16x16x32_bf16(kf[ni][c], qf[qmi][c], st[ni][qmi], 0, 0, 0);

        if (j == jmax) {   // only the last tile can cross the diagonal
            #pragma unroll
            for (int ni = 0; ni < 4; ++ni)
                #pragma unroll
                for (int qmi = 0; qmi < 2; ++qmi)
                    #pragma unroll
                    for (int reg = 0; reg < 4; ++reg) {
                        int key = j * 64 + ni * 16 + quad * 4 + reg;
                        int q   = qbase + qmi * 16 + lr;
                        if (key > q) st[ni][qmi][reg] = -3.0e38f;
                    }
        }

        #pragma unroll
        for (int qmi = 0; qmi < 2; ++qmi) {
            float mx = st[0][qmi][0];
            #pragma unroll
            for (int ni = 0; ni < 4; ++ni)
                #pragma unroll
                for (int reg = 0; reg < 4; ++reg) mx = fmaxf(mx, st[ni][qmi][reg]);
            mx = fmaxf(mx, __shfl_xor(mx, 16, 64));
            mx = fmaxf(mx, __shfl_xor(mx, 32, 64));
            float mnew  = fmaxf(m_r[qmi], mx);
            float alpha = __expf(m_r[qmi] - mnew);
            m_r[qmi] = mnew;

            float rs = 0.f;
            #pragma unroll
            for (int ni = 0; ni < 4; ++ni) {
                unsigned pb[4];
                #pragma unroll
                for (int reg = 0; reg < 4; ++reg) {
                    float p = __expf(st[ni][qmi][reg] - mnew);
                    pb[reg] = f2bf(p);
                    rs += bf2f((u16)pb[reg]);
                }
                uint2 pk;
                pk.x = pb[0] | (pb[1] << 16);
                pk.y = pb[2] | (pb[3] << 16);
                *(uint2*)&Ps[wave][qmi][lr][ni * 16 + quad * 4] = pk;   // packed b64, same-wave
            }
            rs += __shfl_xor(rs, 16, 64);
            rs += __shfl_xor(rs, 32, 64);
            l_r[qmi] = l_r[qmi] * alpha + rs;
            #pragma unroll
            for (int dmi = 0; dmi < 4; ++dmi)
                #pragma unroll
                for (int reg = 0; reg < 4; ++reg) oacc[dmi][qmi][reg] *= alpha;
        }

        #pragma unroll
        for (int c = 0; c < 2; ++c) {
            short8 pf[2];
            #pragma unroll
            for (int qmi = 0; qmi < 2; ++qmi)
                pf[qmi] = *(const short8*)&Ps[wave][qmi][lr][c * 32 + quad * 8];
            #pragma unroll
            for (int dmi = 0; dmi < 4; ++dmi) {
                short8 vf = *(const short8*)&Vt[base + (size_t)(dmi * 16 + lr) * 2048 + j * 64 + c * 32 + quad * 8];
                #pragma unroll
                for (int qmi = 0; qmi < 2; ++qmi)
                    oacc[dmi][qmi] = __builtin_amdgcn_mfma_f32_16x16x32_bf16(vf, pf[qmi], oacc[dmi][qmi], 0, 0, 0);
            }
        }
    }

    const int b = bh >> 4, h = bh & 15;
    #pragma unroll
    for (int qmi = 0; qmi < 2; ++qmi) {
        int s = qbase + qmi * 16 + lr;
        float rl = 1.0f / l_r[qmi];
        #pragma unroll
        for (int dmi = 0; dmi < 4; ++dmi) {
            unsigned ob[4];
            #pragma unroll
            for (int reg = 0; reg < 4; ++reg) ob[reg] = f2bf(oacc[dmi][qmi][reg] * rl);
            uint2 pk;
            pk.x = ob[0] | (ob[1] << 16);
            pk.y = ob[2] | (ob[3] << 16);
            *(uint2*)&O[((size_t)(b * 2048 + s)) * 1024 + h * 64 + dmi * 16 + quad * 4] = pk;
        }
    }
}

extern "C" void kernel_launch(void* const* d_in, const int* in_sizes, int n_in,
                              void* d_out, int out_size, void* d_ws, size_t ws_size,
                              hipStream_t stream) {
    const float* x  = (const float*)d_in[0];
    const float* Wq = (const float*)d_in[1];
    const float* Wk = (const float*)d_in[2];
    const float* Wv = (const float*)d_in[3];
    const float* Wo = (const float*)d_in[4];

    // workspace (u16 units): xb 8.4M | wq,wk,wv,wo 1M each | Q,K,Vt 8.4M each.
    // O aliases xb (x dead after the V GEMM; O written only by attn afterwards).
    u16* xb  = (u16*)d_ws;
    u16* wqb = xb + 8388608;
    u16* wkb = wqb + 1048576;
    u16* wvb = wkb + 1048576;
    u16* wob = wvb + 1048576;
    u16* Qb  = wob + 1048576;
    u16* Kb  = Qb + 8388608;
    u16* Vtb = Kb + 8388608;
    u16* Ob  = xb;   // alias

    convert_all<<<6144, 256, 0, stream>>>(x, Wq, Wk, Wv, Wo, xb, wqb, wkb, wvb, wob);

    gemm128<0><<<dim3(8, 64), 256, 0, stream>>>(xb, wqb, Qb, 1024, 1024, 0.125f);  // Q, pre-scaled
    gemm128<0><<<dim3(8, 64), 256, 0, stream>>>(xb, wkb, Kb, 1024, 1024, 1.0f);    // K
    gemm128<1><<<dim3(64, 8), 256, 0, stream>>>(wvb, xb, Vtb, 8192, 1024, 1.0f);   // V^T = Wv * x^T

    attn_kernel<<<1024, 256, 0, stream>>>(Qb, Kb, Vtb, Ob);

    gemm128<2><<<dim3(8, 64), 256, 0, stream>>>(Ob, wob, (float*)d_out, 1024, 1024, 1.0f);
}